// Round 1
// baseline (1864.154 us; speedup 1.0000x reference)
//
#include <hip/hip_runtime.h>
#include <math.h>

#define BB 8
#define NN 1024
#define KNN 20
#define TS 64
#define BK 16

__device__ __forceinline__ float gelu_erf(float x) {
    return 0.5f * x * (1.0f + erff(x * 0.70710678118654752440f));
}

// ---- transpose x (B,C,N) -> x0 (B,N,3) ----
__global__ void k_transpose(const float* __restrict__ x, float* __restrict__ x0) {
    int t = blockIdx.x * blockDim.x + threadIdx.x;
    if (t >= BB * NN) return;
    int b = t / NN, n = t % NN;
    #pragma unroll
    for (int c = 0; c < 3; ++c) x0[(size_t)t * 3 + c] = x[((size_t)b * 3 + c) * NN + n];
}

// ---- per-row squared norm: rows of A (B*N rows, Kc cols, row stride SA) ----
__global__ void k_rowsq(const float* __restrict__ A, int Kc, int SA, float* __restrict__ sq) {
    int r = blockIdx.x * blockDim.x + threadIdx.x;
    if (r >= BB * NN) return;
    const float* a = A + (size_t)r * SA;
    float s = 0.f;
    for (int c = 0; c < Kc; ++c) s = fmaf(a[c], a[c], s);
    sq[r] = s;
}

// ---- negd[b,n,m] = 2*dot(x_n,x_m) - sq_n - sq_m ----
__global__ void k_negd(const float* __restrict__ X, int Kc, int SA,
                       const float* __restrict__ sq, float* __restrict__ negd) {
    int b = blockIdx.z;
    int n0 = blockIdx.y * TS, m0 = blockIdx.x * TS;
    const float* Xb = X + (size_t)b * NN * SA;
    __shared__ float As[BK][TS + 4];
    __shared__ float Bs[BK][TS + 4];
    int t = threadIdx.x;
    int ty = t / 16, tx = t % 16;
    float acc[4][4] = {};
    for (int k0 = 0; k0 < Kc; k0 += BK) {
        int r = t / 4, kc = (t % 4) * 4;
        const float* srcA = Xb + (size_t)(n0 + r) * SA + k0 + kc;
        const float* srcB = Xb + (size_t)(m0 + r) * SA + k0 + kc;
        #pragma unroll
        for (int i = 0; i < 4; ++i) {
            As[kc + i][r] = (k0 + kc + i < Kc) ? srcA[i] : 0.f;
            Bs[kc + i][r] = (k0 + kc + i < Kc) ? srcB[i] : 0.f;
        }
        __syncthreads();
        #pragma unroll
        for (int kk = 0; kk < BK; ++kk) {
            float av[4], bv[4];
            #pragma unroll
            for (int i = 0; i < 4; ++i) av[i] = As[kk][ty * 4 + i];
            #pragma unroll
            for (int j = 0; j < 4; ++j) bv[j] = Bs[kk][tx * 4 + j];
            #pragma unroll
            for (int i = 0; i < 4; ++i)
                #pragma unroll
                for (int j = 0; j < 4; ++j) acc[i][j] = fmaf(av[i], bv[j], acc[i][j]);
        }
        __syncthreads();
    }
    const float* sqb = sq + (size_t)b * NN;
    float* out = negd + ((size_t)b * NN + n0) * NN + m0;
    #pragma unroll
    for (int i = 0; i < 4; ++i)
        #pragma unroll
        for (int j = 0; j < 4; ++j) {
            int n = ty * 4 + i, m = tx * 4 + j;
            out[(size_t)n * NN + m] = 2.f * acc[i][j] - sqb[n0 + n] - sqb[m0 + m];
        }
}

// ---- top-k=20 per row of negd (argmax-and-mask, tie-break lower index) ----
__global__ void k_topk(const float* __restrict__ negd, int* __restrict__ idxout) {
    int row = blockIdx.x;
    const float* d = negd + (size_t)row * NN;
    __shared__ float vals[NN];
    __shared__ float rv[256];
    __shared__ int ri[256];
    int t = threadIdx.x;
    for (int i = t; i < NN; i += 256) vals[i] = d[i];
    __syncthreads();
    for (int it = 0; it < KNN; ++it) {
        float bv = -INFINITY; int bi = NN;
        for (int i = t; i < NN; i += 256) {
            float v = vals[i];
            if (v > bv || (v == bv && i < bi)) { bv = v; bi = i; }
        }
        rv[t] = bv; ri[t] = bi;
        __syncthreads();
        for (int s = 128; s > 0; s >>= 1) {
            if (t < s) {
                float ov = rv[t + s]; int oi = ri[t + s];
                if (ov > rv[t] || (ov == rv[t] && oi < ri[t])) { rv[t] = ov; ri[t] = oi; }
            }
            __syncthreads();
        }
        if (t == 0) { idxout[(size_t)row * KNN + it] = ri[0]; vals[ri[0]] = -INFINITY; }
        __syncthreads();
    }
}

// ---- build Wt (C x 2O): [:,0:O]=W[:, :C]^T ; [:,O:2O]=(W[:,C:]-W[:,:C])^T ----
__global__ void k_prep_wt(const float* __restrict__ W, int Cc, int O, float* __restrict__ Wt) {
    int t = blockIdx.x * blockDim.x + threadIdx.x;
    if (t >= Cc * O) return;
    int c = t / O, o = t % O;
    float w0 = W[(size_t)o * 2 * Cc + c];
    float w1 = W[(size_t)o * 2 * Cc + Cc + c];
    Wt[(size_t)c * 2 * O + o] = w0;
    Wt[(size_t)c * 2 * O + O + o] = w1 - w0;
}

// ---- plain transpose W (O,K) -> Wt (K,O) for block 5 ----
__global__ void k_prep_wt5(const float* __restrict__ W, int Kc, int O, float* __restrict__ Wt) {
    int t = blockIdx.x * blockDim.x + threadIdx.x;
    if (t >= Kc * O) return;
    int c = t / O, o = t % O;
    Wt[(size_t)c * O + o] = W[(size_t)o * Kc + c];
}

// ---- generic tiled fp32 GEMM: C(M x Nc) = A(M x Kc, stride SA) * Bm(Kc x Nc) ----
__global__ void k_gemm(const float* __restrict__ A, int SA, const float* __restrict__ Bm,
                       float* __restrict__ Cout, int Kc, int Nc) {
    int n0c = blockIdx.x * TS;
    int m0 = blockIdx.y * TS;
    __shared__ float As[BK][TS + 4];
    __shared__ float Bs[BK][TS + 4];
    int t = threadIdx.x;
    int ty = t / 16, tx = t % 16;
    float acc[4][4] = {};
    for (int k0 = 0; k0 < Kc; k0 += BK) {
        {
            int r = t / 4, kc = (t % 4) * 4;
            const float* srcA = A + (size_t)(m0 + r) * SA + k0 + kc;
            #pragma unroll
            for (int i = 0; i < 4; ++i)
                As[kc + i][r] = (k0 + kc + i < Kc) ? srcA[i] : 0.f;
            int kr = t / 16, c4 = (t % 16) * 4;
            const float* srcB = Bm + (size_t)(k0 + kr) * Nc + n0c + c4;
            #pragma unroll
            for (int j = 0; j < 4; ++j)
                Bs[kr][c4 + j] = (k0 + kr < Kc) ? srcB[j] : 0.f;
        }
        __syncthreads();
        #pragma unroll
        for (int kk = 0; kk < BK; ++kk) {
            float av[4], bv[4];
            #pragma unroll
            for (int i = 0; i < 4; ++i) av[i] = As[kk][ty * 4 + i];
            #pragma unroll
            for (int j = 0; j < 4; ++j) bv[j] = Bs[kk][tx * 4 + j];
            #pragma unroll
            for (int i = 0; i < 4; ++i)
                #pragma unroll
                for (int j = 0; j < 4; ++j) acc[i][j] = fmaf(av[i], bv[j], acc[i][j]);
        }
        __syncthreads();
    }
    float* out = Cout + (size_t)m0 * Nc + n0c;
    #pragma unroll
    for (int i = 0; i < 4; ++i)
        #pragma unroll
        for (int j = 0; j < 4; ++j)
            out[(size_t)(ty * 4 + i) * Nc + tx * 4 + j] = acc[i][j];
}

// ---- fused gather: h = u[m_j] + w[n]; track min/max per (row,o); accumulate BN sums ----
__global__ void k_gather_stats(const float* __restrict__ uw, const int* __restrict__ idx,
                               int O, float* __restrict__ hmin, float* __restrict__ hmax,
                               float* __restrict__ s1, float* __restrict__ s2) {
    const int R = 16;
    int row0 = blockIdx.x * R;
    int t = threadIdx.x;
    __shared__ int sidx[R][KNN];
    for (int i = t; i < R * KNN; i += 256)
        sidx[i / KNN][i % KNN] = idx[(size_t)(row0 + i / KNN) * KNN + i % KNN];
    __syncthreads();
    int o4 = t * 4;
    if (o4 >= O) return;
    int twoO = 2 * O;
    int bb = row0 / NN;
    const float* ubase = uw + (size_t)bb * NN * twoO;
    float a1[4] = {0, 0, 0, 0}, a2[4] = {0, 0, 0, 0};
    for (int rr = 0; rr < R; ++rr) {
        int nrow = row0 + rr;
        float4 w4 = *(const float4*)(uw + (size_t)nrow * twoO + O + o4);
        float wv[4] = {w4.x, w4.y, w4.z, w4.w};
        float mn[4], mx[4];
        #pragma unroll
        for (int q = 0; q < 4; ++q) { mn[q] = INFINITY; mx[q] = -INFINITY; }
        for (int j = 0; j < KNN; ++j) {
            int m = sidx[rr][j];
            float4 u4 = *(const float4*)(ubase + (size_t)m * twoO + o4);
            float uv[4] = {u4.x, u4.y, u4.z, u4.w};
            #pragma unroll
            for (int q = 0; q < 4; ++q) {
                float h = uv[q] + wv[q];
                mn[q] = fminf(mn[q], h);
                mx[q] = fmaxf(mx[q], h);
                a1[q] += h;
                a2[q] = fmaf(h, h, a2[q]);
            }
        }
        #pragma unroll
        for (int q = 0; q < 4; ++q) {
            hmin[(size_t)nrow * O + o4 + q] = mn[q];
            hmax[(size_t)nrow * O + o4 + q] = mx[q];
        }
    }
    #pragma unroll
    for (int q = 0; q < 4; ++q) {
        atomicAdd(&s1[o4 + q], a1[q]);
        atomicAdd(&s2[o4 + q], a2[q]);
    }
}

// ---- BN finalize: scale/shift per channel ----
__global__ void k_bn_fin(const float* __restrict__ s1, const float* __restrict__ s2,
                         const float* __restrict__ g, const float* __restrict__ b,
                         float cnt_inv, int O, float* __restrict__ scale, float* __restrict__ shift) {
    int o = blockIdx.x * blockDim.x + threadIdx.x;
    if (o >= O) return;
    float mean = s1[o] * cnt_inv;
    float var = s2[o] * cnt_inv - mean * mean;
    float sc = g[o] * rsqrtf(var + 1e-5f);
    scale[o] = sc;
    shift[o] = b[o] - mean * sc;
}

// ---- apply BN+GELU+maxpool via the (min,max) trick; write into xc slice ----
__global__ void k_apply(const float* __restrict__ hmin, const float* __restrict__ hmax,
                        const float* __restrict__ scale, const float* __restrict__ shift,
                        int O, float* __restrict__ outx, int SX) {
    int row = blockIdx.x;
    int o4 = threadIdx.x * 4;
    if (o4 >= O) return;
    #pragma unroll
    for (int q = 0; q < 4; ++q) {
        int o = o4 + q;
        float sc = scale[o], sh = shift[o];
        float va = gelu_erf(fmaf(sc, hmax[(size_t)row * O + o], sh));
        float vb = gelu_erf(fmaf(sc, hmin[(size_t)row * O + o], sh));
        outx[(size_t)row * SX + o] = fmaxf(va, vb);
    }
}

// ---- block5: per-column sum/sumsq over all rows ----
__global__ void k_colstats(const float* __restrict__ A, int Nc,
                           float* __restrict__ s1, float* __restrict__ s2) {
    int o = blockIdx.x * 256 + threadIdx.x;
    int r0 = blockIdx.y * 64;
    float a1 = 0.f, a2 = 0.f;
    for (int r = 0; r < 64; ++r) {
        float v = A[(size_t)(r0 + r) * Nc + o];
        a1 += v;
        a2 = fmaf(v, v, a2);
    }
    atomicAdd(&s1[o], a1);
    atomicAdd(&s2[o], a2);
}

// ---- block5: gelu(bn(h5)) then partial max/sum over n-chunks ----
__global__ void k_apply5(const float* __restrict__ h5, const float* __restrict__ scale,
                         const float* __restrict__ shift, float* __restrict__ pmax,
                         float* __restrict__ psum) {
    int o = blockIdx.x * 256 + threadIdx.x;
    int ch = blockIdx.y;
    int b = blockIdx.z;
    int n0 = ch * (NN / 16);
    float sc = scale[o], sh = shift[o];
    float mx = -INFINITY, sm = 0.f;
    for (int n = n0; n < n0 + NN / 16; ++n) {
        float v = gelu_erf(fmaf(sc, h5[((size_t)b * NN + n) * 1024 + o], sh));
        mx = fmaxf(mx, v);
        sm += v;
    }
    pmax[((size_t)ch * BB + b) * 1024 + o] = mx;
    psum[((size_t)ch * BB + b) * 1024 + o] = sm;
}

__global__ void k_zfin(const float* __restrict__ pmax, const float* __restrict__ psum,
                       float* __restrict__ z) {
    int o = blockIdx.x * 256 + threadIdx.x;
    int b = blockIdx.y;
    float mx = -INFINITY, sm = 0.f;
    for (int ch = 0; ch < 16; ++ch) {
        mx = fmaxf(mx, pmax[((size_t)ch * BB + b) * 1024 + o]);
        sm += psum[((size_t)ch * BB + b) * 1024 + o];
    }
    z[(size_t)b * 2048 + o] = mx;
    z[(size_t)b * 2048 + 1024 + o] = sm * (1.0f / NN);
}

// ---- FC gemv: out[b,o] = sum_i Z[b,i]*W[o,i] (+bias). One wave per o. ----
__global__ void k_fc(const float* __restrict__ Z, int Kc, const float* __restrict__ W,
                     const float* __restrict__ bias, float* __restrict__ out, int Oc) {
    int o = blockIdx.x;
    int lane = threadIdx.x;
    float acc[BB];
    #pragma unroll
    for (int b = 0; b < BB; ++b) acc[b] = 0.f;
    const float* wrow = W + (size_t)o * Kc;
    for (int i = lane; i < Kc; i += 64) {
        float wv = wrow[i];
        #pragma unroll
        for (int b = 0; b < BB; ++b) acc[b] = fmaf(Z[(size_t)b * Kc + i], wv, acc[b]);
    }
    #pragma unroll
    for (int s = 32; s > 0; s >>= 1) {
        #pragma unroll
        for (int b = 0; b < BB; ++b) acc[b] += __shfl_xor(acc[b], s);
    }
    if (lane == 0) {
        float bv = bias ? bias[o] : 0.f;
        #pragma unroll
        for (int b = 0; b < BB; ++b) out[(size_t)b * Oc + o] = acc[b] + bv;
    }
}

// ---- BN over batch (8) + leaky_relu(0.2), in-place ----
__global__ void k_fcbn(float* __restrict__ zz, const float* __restrict__ g,
                       const float* __restrict__ b, int Oc) {
    int o = blockIdx.x * blockDim.x + threadIdx.x;
    if (o >= Oc) return;
    float m = 0.f;
    #pragma unroll
    for (int q = 0; q < BB; ++q) m += zz[(size_t)q * Oc + o];
    m *= (1.0f / BB);
    float v = 0.f;
    #pragma unroll
    for (int q = 0; q < BB; ++q) { float d = zz[(size_t)q * Oc + o] - m; v = fmaf(d, d, v); }
    v *= (1.0f / BB);
    float sc = g[o] * rsqrtf(v + 1e-5f);
    #pragma unroll
    for (int q = 0; q < BB; ++q) {
        float y = fmaf(zz[(size_t)q * Oc + o] - m, sc, b[o]);
        zz[(size_t)q * Oc + o] = (y >= 0.f) ? y : 0.2f * y;
    }
}

extern "C" void kernel_launch(void* const* d_in, const int* in_sizes, int n_in,
                              void* d_out, int out_size, void* d_ws, size_t ws_size,
                              hipStream_t stream) {
    (void)in_sizes; (void)n_in; (void)out_size; (void)ws_size;
    const float* x   = (const float*)d_in[0];
    // d_in[1] is k (=20), hard-coded as KNN
    const float* W1  = (const float*)d_in[2];
    const float* g1  = (const float*)d_in[3];
    const float* b1  = (const float*)d_in[4];
    const float* W2  = (const float*)d_in[5];
    const float* g2  = (const float*)d_in[6];
    const float* b2  = (const float*)d_in[7];
    const float* W3  = (const float*)d_in[8];
    const float* g3  = (const float*)d_in[9];
    const float* b3  = (const float*)d_in[10];
    const float* W4  = (const float*)d_in[11];
    const float* g4  = (const float*)d_in[12];
    const float* b4  = (const float*)d_in[13];
    const float* W5  = (const float*)d_in[14];
    const float* g5  = (const float*)d_in[15];
    const float* b5  = (const float*)d_in[16];
    const float* Wl1 = (const float*)d_in[17];
    const float* g6  = (const float*)d_in[18];
    const float* b6  = (const float*)d_in[19];
    const float* Wl2 = (const float*)d_in[20];
    const float* bl2 = (const float*)d_in[21];
    const float* g7  = (const float*)d_in[22];
    const float* b7  = (const float*)d_in[23];
    const float* Wl3 = (const float*)d_in[24];
    const float* bl3 = (const float*)d_in[25];

    // ---- workspace carving ----
    char* p = (char*)d_ws;
    auto carve = [&](size_t nbytes) {
        char* q = p;
        p += (nbytes + 255) & ~(size_t)255;
        return (void*)q;
    };
    float* x0    = (float*)carve((size_t)BB * NN * 3 * 4);
    float* sq    = (float*)carve((size_t)BB * NN * 4);
    float* negd  = (float*)carve((size_t)BB * NN * NN * 4);     // also hmin/hmax after topk
    int*   idx   = (int*)carve((size_t)BB * NN * KNN * 4);
    float* Wt    = (float*)carve((size_t)960 * 1024 * 4);
    float* uw    = (float*)carve((size_t)BB * NN * 1024 * 4);   // u|w rows; also h5
    float* xc    = (float*)carve((size_t)BB * NN * 960 * 4);
    float* s1    = (float*)carve(2048 * 4);
    float* s2    = s1 + 1024;
    float* scale = (float*)carve(1024 * 4);
    float* shiftv= (float*)carve(1024 * 4);
    float* pmax  = (float*)carve((size_t)16 * BB * 1024 * 4);
    float* psum  = (float*)carve((size_t)16 * BB * 1024 * 4);
    float* z     = (float*)carve((size_t)BB * 2048 * 4);
    float* z1    = (float*)carve((size_t)BB * 512 * 4);
    float* z2    = (float*)carve((size_t)BB * 256 * 4);
    float* hmin  = negd;
    float* hmax  = negd + (size_t)BB * NN * 512;

    k_transpose<<<dim3((BB * NN + 255) / 256), dim3(256), 0, stream>>>(x, x0);

    const float* Ws[4] = {W1, W2, W3, W4};
    const float* gs[4] = {g1, g2, g3, g4};
    const float* bs[4] = {b1, b2, b3, b4};
    int Cs[4] = {3, 64, 128, 256};
    int Os[4] = {64, 128, 256, 512};
    const float* xins[4] = {x0, xc + 0, xc + 64, xc + 192};
    int SAs[4] = {3, 960, 960, 960};
    int coloff[4] = {0, 64, 192, 448};

    for (int blk = 0; blk < 4; ++blk) {
        int C = Cs[blk], O = Os[blk];
        const float* xin = xins[blk];
        int SA = SAs[blk];
        k_rowsq<<<dim3(32), dim3(256), 0, stream>>>(xin, C, SA, sq);
        k_negd<<<dim3(NN / TS, NN / TS, BB), dim3(256), 0, stream>>>(xin, C, SA, sq, negd);
        k_topk<<<dim3(BB * NN), dim3(256), 0, stream>>>(negd, idx);
        k_prep_wt<<<dim3((C * O + 255) / 256), dim3(256), 0, stream>>>(Ws[blk], C, O, Wt);
        k_gemm<<<dim3(2 * O / TS, BB * NN / TS), dim3(256), 0, stream>>>(xin, SA, Wt, uw, C, 2 * O);
        hipMemsetAsync(s1, 0, 2048 * 4, stream);
        k_gather_stats<<<dim3(BB * NN / 16), dim3(256), 0, stream>>>(uw, idx, O, hmin, hmax, s1, s2);
        k_bn_fin<<<dim3((O + 255) / 256), dim3(256), 0, stream>>>(
            s1, s2, gs[blk], bs[blk], 1.0f / ((float)BB * NN * KNN), O, scale, shiftv);
        k_apply<<<dim3(BB * NN), dim3(128), 0, stream>>>(hmin, hmax, scale, shiftv, O,
                                                         xc + coloff[blk], 960);
    }

    // ---- block 5: h5 = W5 @ xc ----
    k_prep_wt5<<<dim3((960 * 1024 + 255) / 256), dim3(256), 0, stream>>>(W5, 960, 1024, Wt);
    k_gemm<<<dim3(1024 / TS, BB * NN / TS), dim3(256), 0, stream>>>(xc, 960, Wt, uw, 960, 1024);
    hipMemsetAsync(s1, 0, 2048 * 4, stream);
    k_colstats<<<dim3(4, BB * NN / 64), dim3(256), 0, stream>>>(uw, 1024, s1, s2);
    k_bn_fin<<<dim3(4), dim3(256), 0, stream>>>(s1, s2, g5, b5, 1.0f / ((float)BB * NN), 1024,
                                                scale, shiftv);
    k_apply5<<<dim3(4, 16, BB), dim3(256), 0, stream>>>(uw, scale, shiftv, pmax, psum);
    k_zfin<<<dim3(4, BB), dim3(256), 0, stream>>>(pmax, psum, z);

    // ---- FC head ----
    k_fc<<<dim3(512), dim3(64), 0, stream>>>(z, 2048, Wl1, (const float*)nullptr, z1, 512);
    k_fcbn<<<dim3(2), dim3(256), 0, stream>>>(z1, g6, b6, 512);
    k_fc<<<dim3(256), dim3(64), 0, stream>>>(z1, 512, Wl2, bl2, z2, 256);
    k_fcbn<<<dim3(1), dim3(256), 0, stream>>>(z2, g7, b7, 256);
    k_fc<<<dim3(40), dim3(64), 0, stream>>>(z2, 256, Wl3, bl3, (float*)d_out, 40);
}

// Round 2
// 1412.580 us; speedup vs baseline: 1.3197x; 1.3197x over previous
//
#include <hip/hip_runtime.h>
#include <math.h>

#define BB 8
#define NN 1024
#define KNN 20

__device__ __forceinline__ float gelu_erf(float x) {
    return 0.5f * x * (1.0f + erff(x * 0.70710678118654752440f));
}

// ---- transpose x (B,C,N) -> x0 (B,N,3) ----
__global__ void k_transpose(const float* __restrict__ x, float* __restrict__ x0) {
    int t = blockIdx.x * blockDim.x + threadIdx.x;
    if (t >= BB * NN) return;
    int b = t / NN, n = t % NN;
    #pragma unroll
    for (int c = 0; c < 3; ++c) x0[(size_t)t * 3 + c] = x[((size_t)b * 3 + c) * NN + n];
}

// ---- per-row squared norm ----
__global__ void k_rowsq(const float* __restrict__ A, int Kc, int SA, float* __restrict__ sq) {
    int r = blockIdx.x * blockDim.x + threadIdx.x;
    if (r >= BB * NN) return;
    const float* a = A + (size_t)r * SA;
    float s = 0.f;
    for (int c = 0; c < Kc; ++c) s = fmaf(a[c], a[c], s);
    sq[r] = s;
}

// ============ 128x128 tiled fp32 GEMM, 8x8 per thread (2x2 of 4x4) ============
// EPI==0: C(M x Nc) = A(M x Kc, stride SA) * Bm(Kc x Nc row-major)
// EPI==1: negd[b,n,m] = 2*dot(x_n,x_m) - sq_n - sq_m  (A=Bm=X per batch, z=batch)
template <int EPI>
__global__ void k_gemm128(const float* __restrict__ A0, int SA,
                          const float* __restrict__ B0,
                          float* __restrict__ C0, int Kc, int Nc,
                          const float* __restrict__ sq0) {
    const float* A = A0;
    const float* Bm = B0;
    float* Cout = C0;
    const float* sqb = sq0;
    if (EPI == 1) {
        int bz = blockIdx.z;
        A = A0 + (size_t)bz * NN * SA;
        Bm = A;
        Cout = C0 + (size_t)bz * NN * NN;
        sqb = sq0 + (size_t)bz * NN;
    }
    int m0 = blockIdx.y * 128, n0 = blockIdx.x * 128;
    __shared__ float As[16][132];
    __shared__ float Bs[16][132];
    int t = threadIdx.x;
    int tx = t & 15, ty = t >> 4;
    float acc[2][2][4][4] = {};
    for (int k0 = 0; k0 < Kc; k0 += 16) {
        {
            // A tile: 128 rows x 16 k, stored transposed As[k][m]
            int r = t >> 1, kb = (t & 1) * 8;
            const float* src = A + (size_t)(m0 + r) * SA + k0 + kb;
            #pragma unroll
            for (int i = 0; i < 8; ++i)
                As[kb + i][r] = (k0 + kb + i < Kc) ? src[i] : 0.f;
            if (EPI == 1) {
                const float* srcb = Bm + (size_t)(n0 + r) * SA + k0 + kb;
                #pragma unroll
                for (int i = 0; i < 8; ++i)
                    Bs[kb + i][r] = (k0 + kb + i < Kc) ? srcb[i] : 0.f;
            } else {
                // B tile: 16 k-rows x 128 cols, straight
                int kr = t >> 4, c8 = (t & 15) * 8;
                if (k0 + kr < Kc) {
                    const float* srcb = Bm + (size_t)(k0 + kr) * Nc + n0 + c8;
                    float4 f0 = *(const float4*)(srcb);
                    float4 f1 = *(const float4*)(srcb + 4);
                    *(float4*)&Bs[kr][c8] = f0;
                    *(float4*)&Bs[kr][c8 + 4] = f1;
                } else {
                    float4 zz = make_float4(0.f, 0.f, 0.f, 0.f);
                    *(float4*)&Bs[kr][c8] = zz;
                    *(float4*)&Bs[kr][c8 + 4] = zz;
                }
            }
        }
        __syncthreads();
        #pragma unroll
        for (int kk = 0; kk < 16; ++kk) {
            float4 a0 = *(const float4*)&As[kk][ty * 4];
            float4 a1 = *(const float4*)&As[kk][64 + ty * 4];
            float4 b0 = *(const float4*)&Bs[kk][tx * 4];
            float4 b1 = *(const float4*)&Bs[kk][64 + tx * 4];
            float av[2][4] = {{a0.x, a0.y, a0.z, a0.w}, {a1.x, a1.y, a1.z, a1.w}};
            float bv[2][4] = {{b0.x, b0.y, b0.z, b0.w}, {b1.x, b1.y, b1.z, b1.w}};
            #pragma unroll
            for (int hm = 0; hm < 2; ++hm)
                #pragma unroll
                for (int hn = 0; hn < 2; ++hn)
                    #pragma unroll
                    for (int i = 0; i < 4; ++i)
                        #pragma unroll
                        for (int j = 0; j < 4; ++j)
                            acc[hm][hn][i][j] = fmaf(av[hm][i], bv[hn][j], acc[hm][hn][i][j]);
        }
        __syncthreads();
    }
    if (EPI == 0) {
        #pragma unroll
        for (int hm = 0; hm < 2; ++hm)
            #pragma unroll
            for (int i = 0; i < 4; ++i) {
                int m = m0 + hm * 64 + ty * 4 + i;
                float* crow = Cout + (size_t)m * Nc + n0;
                #pragma unroll
                for (int hn = 0; hn < 2; ++hn) {
                    float4 v = make_float4(acc[hm][hn][i][0], acc[hm][hn][i][1],
                                           acc[hm][hn][i][2], acc[hm][hn][i][3]);
                    *(float4*)&crow[hn * 64 + tx * 4] = v;
                }
            }
    } else {
        #pragma unroll
        for (int hm = 0; hm < 2; ++hm)
            #pragma unroll
            for (int i = 0; i < 4; ++i) {
                int m = m0 + hm * 64 + ty * 4 + i;
                float sm = sqb[m];
                float* crow = Cout + (size_t)m * NN + n0;
                #pragma unroll
                for (int hn = 0; hn < 2; ++hn) {
                    float4 sn = *(const float4*)&sqb[n0 + hn * 64 + tx * 4];
                    float4 v;
                    v.x = 2.f * acc[hm][hn][i][0] - sm - sn.x;
                    v.y = 2.f * acc[hm][hn][i][1] - sm - sn.y;
                    v.z = 2.f * acc[hm][hn][i][2] - sm - sn.z;
                    v.w = 2.f * acc[hm][hn][i][3] - sm - sn.w;
                    *(float4*)&crow[hn * 64 + tx * 4] = v;
                }
            }
    }
}

// ---- top-k=20 per row: one wave per row, register-resident, shuffle argmax ----
__global__ void k_topk(const float* __restrict__ negd, int* __restrict__ idxout) {
    int row = blockIdx.x * 4 + (threadIdx.x >> 6);
    int lane = threadIdx.x & 63;
    const float* d = negd + (size_t)row * NN;
    float v[16];
    #pragma unroll
    for (int j = 0; j < 16; ++j) v[j] = d[j * 64 + lane];
    float lv = v[0];
    int lc = lane;
    #pragma unroll
    for (int j = 1; j < 16; ++j) {
        int c = j * 64 + lane;
        if (v[j] > lv) { lv = v[j]; lc = c; }  // strict >: keeps lowest index on tie
    }
    for (int it = 0; it < KNN; ++it) {
        float tv = lv;
        int tc = lc;
        #pragma unroll
        for (int s = 32; s >= 1; s >>= 1) {
            float ov = __shfl_xor(tv, s);
            int oc = __shfl_xor(tc, s);
            if (ov > tv || (ov == tv && oc < tc)) { tv = ov; tc = oc; }
        }
        if (lane == 0) idxout[(size_t)row * KNN + it] = tc;
        if ((tc & 63) == lane) {
            int jd = tc >> 6;
            #pragma unroll
            for (int j = 0; j < 16; ++j)
                if (j == jd) v[j] = -INFINITY;
            lv = -INFINITY;
            lc = 0x7fffffff;
            #pragma unroll
            for (int j = 0; j < 16; ++j) {
                int c = j * 64 + lane;
                if (v[j] > lv || (v[j] == lv && c < lc)) { lv = v[j]; lc = c; }
            }
        }
    }
}

// ---- build Wt (C x 2O): [:,0:O]=W[:, :C]^T ; [:,O:2O]=(W[:,C:]-W[:,:C])^T ----
__global__ void k_prep_wt(const float* __restrict__ W, int Cc, int O, float* __restrict__ Wt) {
    int t = blockIdx.x * blockDim.x + threadIdx.x;
    if (t >= Cc * O) return;
    int c = t / O, o = t % O;
    float w0 = W[(size_t)o * 2 * Cc + c];
    float w1 = W[(size_t)o * 2 * Cc + Cc + c];
    Wt[(size_t)c * 2 * O + o] = w0;
    Wt[(size_t)c * 2 * O + O + o] = w1 - w0;
}

// ---- plain transpose W (O,K) -> Wt (K,O) for block 5 ----
__global__ void k_prep_wt5(const float* __restrict__ W, int Kc, int O, float* __restrict__ Wt) {
    int t = blockIdx.x * blockDim.x + threadIdx.x;
    if (t >= Kc * O) return;
    int c = t / O, o = t % O;
    Wt[(size_t)c * O + o] = W[(size_t)o * Kc + c];
}

// ---- fused gather: h = u[m_j] + w[n]; min/max per (row,o); BN sums ----
__global__ void k_gather_stats(const float* __restrict__ uw, const int* __restrict__ idx,
                               int O, float* __restrict__ hmin, float* __restrict__ hmax,
                               float* __restrict__ s1, float* __restrict__ s2) {
    const int R = 16;
    int row0 = blockIdx.x * R;
    int t = threadIdx.x;
    __shared__ int sidx[R][KNN];
    for (int i = t; i < R * KNN; i += 256)
        sidx[i / KNN][i % KNN] = idx[(size_t)(row0 + i / KNN) * KNN + i % KNN];
    __syncthreads();
    int o4 = t * 4;
    if (o4 >= O) return;
    int twoO = 2 * O;
    int bb = row0 / NN;
    const float* ubase = uw + (size_t)bb * NN * twoO;
    float a1[4] = {0, 0, 0, 0}, a2[4] = {0, 0, 0, 0};
    for (int rr = 0; rr < R; ++rr) {
        int nrow = row0 + rr;
        float4 w4 = *(const float4*)(uw + (size_t)nrow * twoO + O + o4);
        float wv[4] = {w4.x, w4.y, w4.z, w4.w};
        float mn[4], mx[4];
        #pragma unroll
        for (int q = 0; q < 4; ++q) { mn[q] = INFINITY; mx[q] = -INFINITY; }
        for (int j = 0; j < KNN; ++j) {
            int m = sidx[rr][j];
            float4 u4 = *(const float4*)(ubase + (size_t)m * twoO + o4);
            float uv[4] = {u4.x, u4.y, u4.z, u4.w};
            #pragma unroll
            for (int q = 0; q < 4; ++q) {
                float h = uv[q] + wv[q];
                mn[q] = fminf(mn[q], h);
                mx[q] = fmaxf(mx[q], h);
                a1[q] += h;
                a2[q] = fmaf(h, h, a2[q]);
            }
        }
        #pragma unroll
        for (int q = 0; q < 4; ++q) {
            hmin[(size_t)nrow * O + o4 + q] = mn[q];
            hmax[(size_t)nrow * O + o4 + q] = mx[q];
        }
    }
    #pragma unroll
    for (int q = 0; q < 4; ++q) {
        atomicAdd(&s1[o4 + q], a1[q]);
        atomicAdd(&s2[o4 + q], a2[q]);
    }
}

// ---- BN finalize ----
__global__ void k_bn_fin(const float* __restrict__ s1, const float* __restrict__ s2,
                         const float* __restrict__ g, const float* __restrict__ b,
                         float cnt_inv, int O, float* __restrict__ scale, float* __restrict__ shift) {
    int o = blockIdx.x * blockDim.x + threadIdx.x;
    if (o >= O) return;
    float mean = s1[o] * cnt_inv;
    float var = s2[o] * cnt_inv - mean * mean;
    float sc = g[o] * rsqrtf(var + 1e-5f);
    scale[o] = sc;
    shift[o] = b[o] - mean * sc;
}

// ---- apply BN+GELU+maxpool via (min,max) trick ----
__global__ void k_apply(const float* __restrict__ hmin, const float* __restrict__ hmax,
                        const float* __restrict__ scale, const float* __restrict__ shift,
                        int O, float* __restrict__ outx, int SX) {
    int row = blockIdx.x;
    int o4 = threadIdx.x * 4;
    if (o4 >= O) return;
    #pragma unroll
    for (int q = 0; q < 4; ++q) {
        int o = o4 + q;
        float sc = scale[o], sh = shift[o];
        float va = gelu_erf(fmaf(sc, hmax[(size_t)row * O + o], sh));
        float vb = gelu_erf(fmaf(sc, hmin[(size_t)row * O + o], sh));
        outx[(size_t)row * SX + o] = fmaxf(va, vb);
    }
}

// ---- block5: per-column sum/sumsq ----
__global__ void k_colstats(const float* __restrict__ A, int Nc,
                           float* __restrict__ s1, float* __restrict__ s2) {
    int o = blockIdx.x * 256 + threadIdx.x;
    int r0 = blockIdx.y * 64;
    float a1 = 0.f, a2 = 0.f;
    for (int r = 0; r < 64; ++r) {
        float v = A[(size_t)(r0 + r) * Nc + o];
        a1 += v;
        a2 = fmaf(v, v, a2);
    }
    atomicAdd(&s1[o], a1);
    atomicAdd(&s2[o], a2);
}

// ---- block5: gelu(bn(h5)) then partial max/sum ----
__global__ void k_apply5(const float* __restrict__ h5, const float* __restrict__ scale,
                         const float* __restrict__ shift, float* __restrict__ pmax,
                         float* __restrict__ psum) {
    int o = blockIdx.x * 256 + threadIdx.x;
    int ch = blockIdx.y;
    int b = blockIdx.z;
    int n0 = ch * (NN / 16);
    float sc = scale[o], sh = shift[o];
    float mx = -INFINITY, sm = 0.f;
    for (int n = n0; n < n0 + NN / 16; ++n) {
        float v = gelu_erf(fmaf(sc, h5[((size_t)b * NN + n) * 1024 + o], sh));
        mx = fmaxf(mx, v);
        sm += v;
    }
    pmax[((size_t)ch * BB + b) * 1024 + o] = mx;
    psum[((size_t)ch * BB + b) * 1024 + o] = sm;
}

__global__ void k_zfin(const float* __restrict__ pmax, const float* __restrict__ psum,
                       float* __restrict__ z) {
    int o = blockIdx.x * 256 + threadIdx.x;
    int b = blockIdx.y;
    float mx = -INFINITY, sm = 0.f;
    for (int ch = 0; ch < 16; ++ch) {
        mx = fmaxf(mx, pmax[((size_t)ch * BB + b) * 1024 + o]);
        sm += psum[((size_t)ch * BB + b) * 1024 + o];
    }
    z[(size_t)b * 2048 + o] = mx;
    z[(size_t)b * 2048 + 1024 + o] = sm * (1.0f / NN);
}

// ---- FC gemv ----
__global__ void k_fc(const float* __restrict__ Z, int Kc, const float* __restrict__ W,
                     const float* __restrict__ bias, float* __restrict__ out, int Oc) {
    int o = blockIdx.x;
    int lane = threadIdx.x;
    float acc[BB];
    #pragma unroll
    for (int b = 0; b < BB; ++b) acc[b] = 0.f;
    const float* wrow = W + (size_t)o * Kc;
    for (int i = lane; i < Kc; i += 64) {
        float wv = wrow[i];
        #pragma unroll
        for (int b = 0; b < BB; ++b) acc[b] = fmaf(Z[(size_t)b * Kc + i], wv, acc[b]);
    }
    #pragma unroll
    for (int s = 32; s > 0; s >>= 1) {
        #pragma unroll
        for (int b = 0; b < BB; ++b) acc[b] += __shfl_xor(acc[b], s);
    }
    if (lane == 0) {
        float bv = bias ? bias[o] : 0.f;
        #pragma unroll
        for (int b = 0; b < BB; ++b) out[(size_t)b * Oc + o] = acc[b] + bv;
    }
}

// ---- BN over batch (8) + leaky_relu(0.2), in-place ----
__global__ void k_fcbn(float* __restrict__ zz, const float* __restrict__ g,
                       const float* __restrict__ b, int Oc) {
    int o = blockIdx.x * blockDim.x + threadIdx.x;
    if (o >= Oc) return;
    float m = 0.f;
    #pragma unroll
    for (int q = 0; q < BB; ++q) m += zz[(size_t)q * Oc + o];
    m *= (1.0f / BB);
    float v = 0.f;
    #pragma unroll
    for (int q = 0; q < BB; ++q) { float d = zz[(size_t)q * Oc + o] - m; v = fmaf(d, d, v); }
    v *= (1.0f / BB);
    float sc = g[o] * rsqrtf(v + 1e-5f);
    #pragma unroll
    for (int q = 0; q < BB; ++q) {
        float y = fmaf(zz[(size_t)q * Oc + o] - m, sc, b[o]);
        zz[(size_t)q * Oc + o] = (y >= 0.f) ? y : 0.2f * y;
    }
}

extern "C" void kernel_launch(void* const* d_in, const int* in_sizes, int n_in,
                              void* d_out, int out_size, void* d_ws, size_t ws_size,
                              hipStream_t stream) {
    (void)in_sizes; (void)n_in; (void)out_size; (void)ws_size;
    const float* x   = (const float*)d_in[0];
    const float* W1  = (const float*)d_in[2];
    const float* g1  = (const float*)d_in[3];
    const float* b1  = (const float*)d_in[4];
    const float* W2  = (const float*)d_in[5];
    const float* g2  = (const float*)d_in[6];
    const float* b2  = (const float*)d_in[7];
    const float* W3  = (const float*)d_in[8];
    const float* g3  = (const float*)d_in[9];
    const float* b3  = (const float*)d_in[10];
    const float* W4  = (const float*)d_in[11];
    const float* g4  = (const float*)d_in[12];
    const float* b4  = (const float*)d_in[13];
    const float* W5  = (const float*)d_in[14];
    const float* g5  = (const float*)d_in[15];
    const float* b5  = (const float*)d_in[16];
    const float* Wl1 = (const float*)d_in[17];
    const float* g6  = (const float*)d_in[18];
    const float* b6  = (const float*)d_in[19];
    const float* Wl2 = (const float*)d_in[20];
    const float* bl2 = (const float*)d_in[21];
    const float* g7  = (const float*)d_in[22];
    const float* b7  = (const float*)d_in[23];
    const float* Wl3 = (const float*)d_in[24];
    const float* bl3 = (const float*)d_in[25];

    char* p = (char*)d_ws;
    auto carve = [&](size_t nbytes) {
        char* q = p;
        p += (nbytes + 255) & ~(size_t)255;
        return (void*)q;
    };
    float* x0    = (float*)carve((size_t)BB * NN * 3 * 4);
    float* sq    = (float*)carve((size_t)BB * NN * 4);
    float* negd  = (float*)carve((size_t)BB * NN * NN * 4);     // also hmin/hmax after topk
    int*   idx   = (int*)carve((size_t)BB * NN * KNN * 4);
    float* Wt    = (float*)carve((size_t)960 * 1024 * 4);
    float* uw    = (float*)carve((size_t)BB * NN * 1024 * 4);   // u|w rows; also h5
    float* xc    = (float*)carve((size_t)BB * NN * 960 * 4);
    float* s1    = (float*)carve(2048 * 4);
    float* s2    = s1 + 1024;
    float* scale = (float*)carve(1024 * 4);
    float* shiftv= (float*)carve(1024 * 4);
    float* pmax  = (float*)carve((size_t)16 * BB * 1024 * 4);
    float* psum  = (float*)carve((size_t)16 * BB * 1024 * 4);
    float* z     = (float*)carve((size_t)BB * 2048 * 4);
    float* z1    = (float*)carve((size_t)BB * 512 * 4);
    float* z2    = (float*)carve((size_t)BB * 256 * 4);
    float* hmin  = negd;
    float* hmax  = negd + (size_t)BB * NN * 512;

    k_transpose<<<dim3((BB * NN + 255) / 256), dim3(256), 0, stream>>>(x, x0);

    const float* Ws[4] = {W1, W2, W3, W4};
    const float* gs[4] = {g1, g2, g3, g4};
    const float* bs[4] = {b1, b2, b3, b4};
    int Cs[4] = {3, 64, 128, 256};
    int Os[4] = {64, 128, 256, 512};
    const float* xins[4] = {x0, xc + 0, xc + 64, xc + 192};
    int SAs[4] = {3, 960, 960, 960};
    int coloff[4] = {0, 64, 192, 448};

    for (int blk = 0; blk < 4; ++blk) {
        int C = Cs[blk], O = Os[blk];
        const float* xin = xins[blk];
        int SA = SAs[blk];
        k_rowsq<<<dim3(32), dim3(256), 0, stream>>>(xin, C, SA, sq);
        k_gemm128<1><<<dim3(NN / 128, NN / 128, BB), dim3(256), 0, stream>>>(
            xin, SA, xin, negd, C, NN, sq);
        k_topk<<<dim3(BB * NN / 4), dim3(256), 0, stream>>>(negd, idx);
        k_prep_wt<<<dim3((C * O + 255) / 256), dim3(256), 0, stream>>>(Ws[blk], C, O, Wt);
        k_gemm128<0><<<dim3(2 * O / 128, BB * NN / 128, 1), dim3(256), 0, stream>>>(
            xin, SA, Wt, uw, C, 2 * O, (const float*)nullptr);
        hipMemsetAsync(s1, 0, 2048 * 4, stream);
        k_gather_stats<<<dim3(BB * NN / 16), dim3(256), 0, stream>>>(uw, idx, O, hmin, hmax, s1, s2);
        k_bn_fin<<<dim3((O + 255) / 256), dim3(256), 0, stream>>>(
            s1, s2, gs[blk], bs[blk], 1.0f / ((float)BB * NN * KNN), O, scale, shiftv);
        k_apply<<<dim3(BB * NN), dim3(128), 0, stream>>>(hmin, hmax, scale, shiftv, O,
                                                         xc + coloff[blk], 960);
    }

    // ---- block 5 ----
    k_prep_wt5<<<dim3((960 * 1024 + 255) / 256), dim3(256), 0, stream>>>(W5, 960, 1024, Wt);
    k_gemm128<0><<<dim3(1024 / 128, BB * NN / 128, 1), dim3(256), 0, stream>>>(
        xc, 960, Wt, uw, 960, 1024, (const float*)nullptr);
    hipMemsetAsync(s1, 0, 2048 * 4, stream);
    k_colstats<<<dim3(4, BB * NN / 64), dim3(256), 0, stream>>>(uw, 1024, s1, s2);
    k_bn_fin<<<dim3(4), dim3(256), 0, stream>>>(s1, s2, g5, b5, 1.0f / ((float)BB * NN), 1024,
                                                scale, shiftv);
    k_apply5<<<dim3(4, 16, BB), dim3(256), 0, stream>>>(uw, scale, shiftv, pmax, psum);
    k_zfin<<<dim3(4, BB), dim3(256), 0, stream>>>(pmax, psum, z);

    // ---- FC head ----
    k_fc<<<dim3(512), dim3(64), 0, stream>>>(z, 2048, Wl1, (const float*)nullptr, z1, 512);
    k_fcbn<<<dim3(2), dim3(256), 0, stream>>>(z1, g6, b6, 512);
    k_fc<<<dim3(256), dim3(64), 0, stream>>>(z1, 512, Wl2, bl2, z2, 256);
    k_fcbn<<<dim3(1), dim3(256), 0, stream>>>(z2, g7, b7, 256);
    k_fc<<<dim3(40), dim3(64), 0, stream>>>(z2, 256, Wl3, bl3, (float*)d_out, 40);
}

// Round 4
// 1263.437 us; speedup vs baseline: 1.4755x; 1.1180x over previous
//
#include <hip/hip_runtime.h>
#include <math.h>

#define BB 8
#define NN 1024
#define KNN 20

typedef unsigned short u16;
typedef __bf16 bf16x8 __attribute__((ext_vector_type(8)));
typedef float floatx4 __attribute__((ext_vector_type(4)));

__device__ __forceinline__ float gelu_erf(float x) {
    return 0.5f * x * (1.0f + erff(x * 0.70710678118654752440f));
}

__device__ __forceinline__ u16 f2bf(float f) {
    unsigned int u = __float_as_uint(f);
    unsigned int r = (u + 0x7fffu + ((u >> 16) & 1u)) >> 16;
    return (u16)r;
}
__device__ __forceinline__ float bf2f(u16 h) {
    return __uint_as_float(((unsigned int)h) << 16);
}

// ---- transpose x (B,C,N) -> x0 (B,N,3) ----
__global__ void k_transpose(const float* __restrict__ x, float* __restrict__ x0) {
    int t = blockIdx.x * blockDim.x + threadIdx.x;
    if (t >= BB * NN) return;
    int b = t / NN, n = t % NN;
    #pragma unroll
    for (int c = 0; c < 3; ++c) x0[(size_t)t * 3 + c] = x[((size_t)b * 3 + c) * NN + n];
}

// ---- per-row squared norm ----
__global__ void k_rowsq(const float* __restrict__ A, int Kc, int SA, float* __restrict__ sq) {
    int r = blockIdx.x * blockDim.x + threadIdx.x;
    if (r >= BB * NN) return;
    const float* a = A + (size_t)r * SA;
    float s = 0.f;
    for (int c = 0; c < Kc; ++c) s = fmaf(a[c], a[c], s);
    sq[r] = s;
}

// ============ 128x128 tiled fp32 GEMM (negd + edge-block uw) ============
// EPI==0: C(M x Nc) = A(M x Kc, stride SA) * Bm(Kc x Nc row-major)
// EPI==1: negd[b,n,m] = 2*dot(x_n,x_m) - sq_n - sq_m
template <int EPI>
__global__ void k_gemm128(const float* __restrict__ A0, int SA,
                          const float* __restrict__ B0,
                          float* __restrict__ C0, int Kc, int Nc,
                          const float* __restrict__ sq0) {
    const float* A = A0;
    const float* Bm = B0;
    float* Cout = C0;
    const float* sqb = sq0;
    if (EPI == 1) {
        int bz = blockIdx.z;
        A = A0 + (size_t)bz * NN * SA;
        Bm = A;
        Cout = C0 + (size_t)bz * NN * NN;
        sqb = sq0 + (size_t)bz * NN;
    }
    int m0 = blockIdx.y * 128, n0 = blockIdx.x * 128;
    __shared__ float As[16][132];
    __shared__ float Bs[16][132];
    int t = threadIdx.x;
    int tx = t & 15, ty = t >> 4;
    float acc[2][2][4][4] = {};
    for (int k0 = 0; k0 < Kc; k0 += 16) {
        {
            int r = t >> 1, kb = (t & 1) * 8;
            const float* src = A + (size_t)(m0 + r) * SA + k0 + kb;
            #pragma unroll
            for (int i = 0; i < 8; ++i)
                As[kb + i][r] = (k0 + kb + i < Kc) ? src[i] : 0.f;
            if (EPI == 1) {
                const float* srcb = Bm + (size_t)(n0 + r) * SA + k0 + kb;
                #pragma unroll
                for (int i = 0; i < 8; ++i)
                    Bs[kb + i][r] = (k0 + kb + i < Kc) ? srcb[i] : 0.f;
            } else {
                int kr = t >> 4, c8 = (t & 15) * 8;
                if (k0 + kr < Kc) {
                    const float* srcb = Bm + (size_t)(k0 + kr) * Nc + n0 + c8;
                    float4 f0 = *(const float4*)(srcb);
                    float4 f1 = *(const float4*)(srcb + 4);
                    *(float4*)&Bs[kr][c8] = f0;
                    *(float4*)&Bs[kr][c8 + 4] = f1;
                } else {
                    float4 zz = make_float4(0.f, 0.f, 0.f, 0.f);
                    *(float4*)&Bs[kr][c8] = zz;
                    *(float4*)&Bs[kr][c8 + 4] = zz;
                }
            }
        }
        __syncthreads();
        #pragma unroll
        for (int kk = 0; kk < 16; ++kk) {
            float4 a0 = *(const float4*)&As[kk][ty * 4];
            float4 a1 = *(const float4*)&As[kk][64 + ty * 4];
            float4 b0 = *(const float4*)&Bs[kk][tx * 4];
            float4 b1 = *(const float4*)&Bs[kk][64 + tx * 4];
            float av[2][4] = {{a0.x, a0.y, a0.z, a0.w}, {a1.x, a1.y, a1.z, a1.w}};
            float bv[2][4] = {{b0.x, b0.y, b0.z, b0.w}, {b1.x, b1.y, b1.z, b1.w}};
            #pragma unroll
            for (int hm = 0; hm < 2; ++hm)
                #pragma unroll
                for (int hn = 0; hn < 2; ++hn)
                    #pragma unroll
                    for (int i = 0; i < 4; ++i)
                        #pragma unroll
                        for (int j = 0; j < 4; ++j)
                            acc[hm][hn][i][j] = fmaf(av[hm][i], bv[hn][j], acc[hm][hn][i][j]);
        }
        __syncthreads();
    }
    if (EPI == 0) {
        #pragma unroll
        for (int hm = 0; hm < 2; ++hm)
            #pragma unroll
            for (int i = 0; i < 4; ++i) {
                int m = m0 + hm * 64 + ty * 4 + i;
                float* crow = Cout + (size_t)m * Nc + n0;
                #pragma unroll
                for (int hn = 0; hn < 2; ++hn) {
                    float4 v = make_float4(acc[hm][hn][i][0], acc[hm][hn][i][1],
                                           acc[hm][hn][i][2], acc[hm][hn][i][3]);
                    *(float4*)&crow[hn * 64 + tx * 4] = v;
                }
            }
    } else {
        #pragma unroll
        for (int hm = 0; hm < 2; ++hm)
            #pragma unroll
            for (int i = 0; i < 4; ++i) {
                int m = m0 + hm * 64 + ty * 4 + i;
                float sm = sqb[m];
                float* crow = Cout + (size_t)m * NN + n0;
                #pragma unroll
                for (int hn = 0; hn < 2; ++hn) {
                    float4 sn = *(const float4*)&sqb[n0 + hn * 64 + tx * 4];
                    float4 v;
                    v.x = 2.f * acc[hm][hn][i][0] - sm - sn.x;
                    v.y = 2.f * acc[hm][hn][i][1] - sm - sn.y;
                    v.z = 2.f * acc[hm][hn][i][2] - sm - sn.z;
                    v.w = 2.f * acc[hm][hn][i][3] - sm - sn.w;
                    *(float4*)&crow[hn * 64 + tx * 4] = v;
                }
            }
    }
}

// ============ split-bf16 MFMA GEMM: C = A * B^T, ~fp32 accuracy ============
// A = Ahi+Alo (M x K bf16 pairs, stride lda), B likewise (N x K, stride ldb).
// C fp32 (ldc). Tile 128x128, 4 waves 2x2, each 64x64 via 4x4 mfma 16x16x32.
// 3-term product: Ahi*Bhi + Ahi*Blo + Alo*Bhi  (error ~2^-16 relative).
__global__ __launch_bounds__(256) void k_mfma_bt_split(
    const u16* __restrict__ Ahi, const u16* __restrict__ Alo, int lda,
    const u16* __restrict__ Bhi, const u16* __restrict__ Blo, int ldb,
    float* __restrict__ Cout, int ldc, int K) {
    int m0 = blockIdx.y * 128, n0 = blockIdx.x * 128;
    __shared__ u16 sAh[128 * 40];
    __shared__ u16 sAl[128 * 40];
    __shared__ u16 sBh[128 * 40];
    __shared__ u16 sBl[128 * 40];
    int t = threadIdx.x;
    int w = t >> 6, lane = t & 63;
    int wm = (w & 1) * 64, wn = (w >> 1) * 64;
    int q = lane >> 4, lm = lane & 15;
    floatx4 acc[4][4];
    #pragma unroll
    for (int i = 0; i < 4; ++i)
        #pragma unroll
        for (int j = 0; j < 4; ++j) {
            floatx4 z = {0.f, 0.f, 0.f, 0.f};
            acc[i][j] = z;
        }
    for (int k0 = 0; k0 < K; k0 += 32) {
        #pragma unroll
        for (int rep = 0; rep < 2; ++rep) {
            int c = t + rep * 256;
            int row = c >> 2, ko = (c & 3) * 8;
            *(float4*)&sAh[row * 40 + ko] =
                *(const float4*)&Ahi[(size_t)(m0 + row) * lda + k0 + ko];
            *(float4*)&sAl[row * 40 + ko] =
                *(const float4*)&Alo[(size_t)(m0 + row) * lda + k0 + ko];
            *(float4*)&sBh[row * 40 + ko] =
                *(const float4*)&Bhi[(size_t)(n0 + row) * ldb + k0 + ko];
            *(float4*)&sBl[row * 40 + ko] =
                *(const float4*)&Blo[(size_t)(n0 + row) * ldb + k0 + ko];
        }
        __syncthreads();
        bf16x8 ah[4], al[4], bh[4], bl[4];
        #pragma unroll
        for (int i = 0; i < 4; ++i) {
            ah[i] = *(const bf16x8*)&sAh[(wm + i * 16 + lm) * 40 + q * 8];
            al[i] = *(const bf16x8*)&sAl[(wm + i * 16 + lm) * 40 + q * 8];
        }
        #pragma unroll
        for (int j = 0; j < 4; ++j) {
            bh[j] = *(const bf16x8*)&sBh[(wn + j * 16 + lm) * 40 + q * 8];
            bl[j] = *(const bf16x8*)&sBl[(wn + j * 16 + lm) * 40 + q * 8];
        }
        #pragma unroll
        for (int i = 0; i < 4; ++i)
            #pragma unroll
            for (int j = 0; j < 4; ++j) {
                acc[i][j] = __builtin_amdgcn_mfma_f32_16x16x32_bf16(ah[i], bh[j], acc[i][j], 0, 0, 0);
                acc[i][j] = __builtin_amdgcn_mfma_f32_16x16x32_bf16(ah[i], bl[j], acc[i][j], 0, 0, 0);
                acc[i][j] = __builtin_amdgcn_mfma_f32_16x16x32_bf16(al[i], bh[j], acc[i][j], 0, 0, 0);
            }
        __syncthreads();
    }
    #pragma unroll
    for (int i = 0; i < 4; ++i) {
        int rowb = m0 + wm + i * 16 + q * 4;
        #pragma unroll
        for (int j = 0; j < 4; ++j) {
            int col = n0 + wn + j * 16 + lm;
            #pragma unroll
            for (int r = 0; r < 4; ++r)
                Cout[(size_t)(rowb + r) * ldc + col] = acc[i][j][r];
        }
    }
}

// ---- split-convert: rows x width fp32 (stride) -> bf16 hi/lo contiguous ----
__global__ void k_cvt_split(const float* __restrict__ src, int stride, int width, int rows,
                            u16* __restrict__ dhi, u16* __restrict__ dlo) {
    int quads = width >> 2;
    int total = rows * quads;
    int t = blockIdx.x * 256 + threadIdx.x;
    if (t >= total) return;
    int row = t / quads, qd = t % quads;
    float4 v = *(const float4*)&src[(size_t)row * stride + qd * 4];
    ushort4 h, l;
    h.x = f2bf(v.x); l.x = f2bf(v.x - bf2f(h.x));
    h.y = f2bf(v.y); l.y = f2bf(v.y - bf2f(h.y));
    h.z = f2bf(v.z); l.z = f2bf(v.z - bf2f(h.z));
    h.w = f2bf(v.w); l.w = f2bf(v.w - bf2f(h.w));
    *(ushort4*)&dhi[(size_t)row * width + qd * 4] = h;
    *(ushort4*)&dlo[(size_t)row * width + qd * 4] = l;
}

// ---- top-k=20 per row: one wave per row, register-resident, shuffle argmax ----
__global__ void k_topk(const float* __restrict__ negd, int* __restrict__ idxout) {
    int row = blockIdx.x * 4 + (threadIdx.x >> 6);
    int lane = threadIdx.x & 63;
    const float* d = negd + (size_t)row * NN;
    float v[16];
    #pragma unroll
    for (int j = 0; j < 16; ++j) v[j] = d[j * 64 + lane];
    float lv = v[0];
    int lc = lane;
    #pragma unroll
    for (int j = 1; j < 16; ++j) {
        int c = j * 64 + lane;
        if (v[j] > lv) { lv = v[j]; lc = c; }
    }
    for (int it = 0; it < KNN; ++it) {
        float tv = lv;
        int tc = lc;
        #pragma unroll
        for (int s = 32; s >= 1; s >>= 1) {
            float ov = __shfl_xor(tv, s);
            int oc = __shfl_xor(tc, s);
            if (ov > tv || (ov == tv && oc < tc)) { tv = ov; tc = oc; }
        }
        if (lane == 0) idxout[(size_t)row * KNN + it] = tc;
        if ((tc & 63) == lane) {
            int jd = tc >> 6;
            #pragma unroll
            for (int j = 0; j < 16; ++j)
                if (j == jd) v[j] = -INFINITY;
            lv = -INFINITY;
            lc = 0x7fffffff;
            #pragma unroll
            for (int j = 0; j < 16; ++j) {
                int c = j * 64 + lane;
                if (v[j] > lv || (v[j] == lv && c < lc)) { lv = v[j]; lc = c; }
            }
        }
    }
}

// ---- fp32 Wt (C x 2O): [:,0:O]=W[:, :C]^T ; [:,O:2O]=(W[:,C:]-W[:,:C])^T ----
__global__ void k_prep_wt(const float* __restrict__ W, int Cc, int O, float* __restrict__ Wt) {
    int t = blockIdx.x * blockDim.x + threadIdx.x;
    if (t >= Cc * O) return;
    int c = t / O, o = t % O;
    float w0 = W[(size_t)o * 2 * Cc + c];
    float w1 = W[(size_t)o * 2 * Cc + Cc + c];
    Wt[(size_t)c * 2 * O + o] = w0;
    Wt[(size_t)c * 2 * O + O + o] = w1 - w0;
}

// ---- fused gather: h = u[m_j] + w[n]; min/max per (row,o); BN sums ----
__global__ void k_gather_stats(const float* __restrict__ uw, const int* __restrict__ idx,
                               int O, float* __restrict__ hmin, float* __restrict__ hmax,
                               float* __restrict__ s1, float* __restrict__ s2) {
    const int R = 16;
    int row0 = blockIdx.x * R;
    int t = threadIdx.x;
    __shared__ int sidx[R][KNN];
    for (int i = t; i < R * KNN; i += 256)
        sidx[i / KNN][i % KNN] = idx[(size_t)(row0 + i / KNN) * KNN + i % KNN];
    __syncthreads();
    int o4 = t * 4;
    if (o4 >= O) return;
    int twoO = 2 * O;
    int bb = row0 / NN;
    const float* ubase = uw + (size_t)bb * NN * twoO;
    float a1[4] = {0, 0, 0, 0}, a2[4] = {0, 0, 0, 0};
    for (int rr = 0; rr < R; ++rr) {
        int nrow = row0 + rr;
        float4 w4 = *(const float4*)(uw + (size_t)nrow * twoO + O + o4);
        float wv[4] = {w4.x, w4.y, w4.z, w4.w};
        float mn[4], mx[4];
        #pragma unroll
        for (int q = 0; q < 4; ++q) { mn[q] = INFINITY; mx[q] = -INFINITY; }
        for (int j = 0; j < KNN; ++j) {
            int m = sidx[rr][j];
            float4 u4 = *(const float4*)(ubase + (size_t)m * twoO + o4);
            float uv[4] = {u4.x, u4.y, u4.z, u4.w};
            #pragma unroll
            for (int q = 0; q < 4; ++q) {
                float h = uv[q] + wv[q];
                mn[q] = fminf(mn[q], h);
                mx[q] = fmaxf(mx[q], h);
                a1[q] += h;
                a2[q] = fmaf(h, h, a2[q]);
            }
        }
        #pragma unroll
        for (int q = 0; q < 4; ++q) {
            hmin[(size_t)nrow * O + o4 + q] = mn[q];
            hmax[(size_t)nrow * O + o4 + q] = mx[q];
        }
    }
    #pragma unroll
    for (int q = 0; q < 4; ++q) {
        atomicAdd(&s1[o4 + q], a1[q]);
        atomicAdd(&s2[o4 + q], a2[q]);
    }
}

// ---- BN finalize ----
__global__ void k_bn_fin(const float* __restrict__ s1, const float* __restrict__ s2,
                         const float* __restrict__ g, const float* __restrict__ b,
                         float cnt_inv, int O, float* __restrict__ scale, float* __restrict__ shift) {
    int o = blockIdx.x * blockDim.x + threadIdx.x;
    if (o >= O) return;
    float mean = s1[o] * cnt_inv;
    float var = s2[o] * cnt_inv - mean * mean;
    float sc = g[o] * rsqrtf(var + 1e-5f);
    scale[o] = sc;
    shift[o] = b[o] - mean * sc;
}

// ---- apply BN+GELU+maxpool via (min,max) trick ----
__global__ void k_apply(const float* __restrict__ hmin, const float* __restrict__ hmax,
                        const float* __restrict__ scale, const float* __restrict__ shift,
                        int O, float* __restrict__ outx, int SX) {
    int row = blockIdx.x;
    int o4 = threadIdx.x * 4;
    if (o4 >= O) return;
    #pragma unroll
    for (int q = 0; q < 4; ++q) {
        int o = o4 + q;
        float sc = scale[o], sh = shift[o];
        float va = gelu_erf(fmaf(sc, hmax[(size_t)row * O + o], sh));
        float vb = gelu_erf(fmaf(sc, hmin[(size_t)row * O + o], sh));
        outx[(size_t)row * SX + o] = fmaxf(va, vb);
    }
}

// ---- block5: per-column sum/sumsq ----
__global__ void k_colstats(const float* __restrict__ A, int Nc,
                           float* __restrict__ s1, float* __restrict__ s2) {
    int o = blockIdx.x * 256 + threadIdx.x;
    int r0 = blockIdx.y * 64;
    float a1 = 0.f, a2 = 0.f;
    for (int r = 0; r < 64; ++r) {
        float v = A[(size_t)(r0 + r) * Nc + o];
        a1 += v;
        a2 = fmaf(v, v, a2);
    }
    atomicAdd(&s1[o], a1);
    atomicAdd(&s2[o], a2);
}

// ---- block5: gelu(bn(h5)) then partial max/sum ----
__global__ void k_apply5(const float* __restrict__ h5, const float* __restrict__ scale,
                         const float* __restrict__ shift, float* __restrict__ pmax,
                         float* __restrict__ psum) {
    int o = blockIdx.x * 256 + threadIdx.x;
    int ch = blockIdx.y;
    int b = blockIdx.z;
    int n0 = ch * (NN / 16);
    float sc = scale[o], sh = shift[o];
    float mx = -INFINITY, sm = 0.f;
    for (int n = n0; n < n0 + NN / 16; ++n) {
        float v = gelu_erf(fmaf(sc, h5[((size_t)b * NN + n) * 1024 + o], sh));
        mx = fmaxf(mx, v);
        sm += v;
    }
    pmax[((size_t)ch * BB + b) * 1024 + o] = mx;
    psum[((size_t)ch * BB + b) * 1024 + o] = sm;
}

__global__ void k_zfin(const float* __restrict__ pmax, const float* __restrict__ psum,
                       float* __restrict__ z) {
    int o = blockIdx.x * 256 + threadIdx.x;
    int b = blockIdx.y;
    float mx = -INFINITY, sm = 0.f;
    for (int ch = 0; ch < 16; ++ch) {
        mx = fmaxf(mx, pmax[((size_t)ch * BB + b) * 1024 + o]);
        sm += psum[((size_t)ch * BB + b) * 1024 + o];
    }
    z[(size_t)b * 2048 + o] = mx;
    z[(size_t)b * 2048 + 1024 + o] = sm * (1.0f / NN);
}

// ---- FC gemv ----
__global__ void k_fc(const float* __restrict__ Z, int Kc, const float* __restrict__ W,
                     const float* __restrict__ bias, float* __restrict__ out, int Oc) {
    int o = blockIdx.x;
    int lane = threadIdx.x;
    float acc[BB];
    #pragma unroll
    for (int b = 0; b < BB; ++b) acc[b] = 0.f;
    const float* wrow = W + (size_t)o * Kc;
    for (int i = lane; i < Kc; i += 64) {
        float wv = wrow[i];
        #pragma unroll
        for (int b = 0; b < BB; ++b) acc[b] = fmaf(Z[(size_t)b * Kc + i], wv, acc[b]);
    }
    #pragma unroll
    for (int s = 32; s > 0; s >>= 1) {
        #pragma unroll
        for (int b = 0; b < BB; ++b) acc[b] += __shfl_xor(acc[b], s);
    }
    if (lane == 0) {
        float bv = bias ? bias[o] : 0.f;
        #pragma unroll
        for (int b = 0; b < BB; ++b) out[(size_t)b * Oc + o] = acc[b] + bv;
    }
}

// ---- BN over batch (8) + leaky_relu(0.2), in-place ----
__global__ void k_fcbn(float* __restrict__ zz, const float* __restrict__ g,
                       const float* __restrict__ b, int Oc) {
    int o = blockIdx.x * blockDim.x + threadIdx.x;
    if (o >= Oc) return;
    float m = 0.f;
    #pragma unroll
    for (int q = 0; q < BB; ++q) m += zz[(size_t)q * Oc + o];
    m *= (1.0f / BB);
    float v = 0.f;
    #pragma unroll
    for (int q = 0; q < BB; ++q) { float d = zz[(size_t)q * Oc + o] - m; v = fmaf(d, d, v); }
    v *= (1.0f / BB);
    float sc = g[o] * rsqrtf(v + 1e-5f);
    #pragma unroll
    for (int q = 0; q < BB; ++q) {
        float y = fmaf(zz[(size_t)q * Oc + o] - m, sc, b[o]);
        zz[(size_t)q * Oc + o] = (y >= 0.f) ? y : 0.2f * y;
    }
}

extern "C" void kernel_launch(void* const* d_in, const int* in_sizes, int n_in,
                              void* d_out, int out_size, void* d_ws, size_t ws_size,
                              hipStream_t stream) {
    (void)in_sizes; (void)n_in; (void)out_size; (void)ws_size;
    const float* x   = (const float*)d_in[0];
    const float* W1  = (const float*)d_in[2];
    const float* g1  = (const float*)d_in[3];
    const float* b1  = (const float*)d_in[4];
    const float* W2  = (const float*)d_in[5];
    const float* g2  = (const float*)d_in[6];
    const float* b2  = (const float*)d_in[7];
    const float* W3  = (const float*)d_in[8];
    const float* g3  = (const float*)d_in[9];
    const float* b3  = (const float*)d_in[10];
    const float* W4  = (const float*)d_in[11];
    const float* g4  = (const float*)d_in[12];
    const float* b4  = (const float*)d_in[13];
    const float* W5  = (const float*)d_in[14];
    const float* g5  = (const float*)d_in[15];
    const float* b5  = (const float*)d_in[16];
    const float* Wl1 = (const float*)d_in[17];
    const float* g6  = (const float*)d_in[18];
    const float* b6  = (const float*)d_in[19];
    const float* Wl2 = (const float*)d_in[20];
    const float* bl2 = (const float*)d_in[21];
    const float* g7  = (const float*)d_in[22];
    const float* b7  = (const float*)d_in[23];
    const float* Wl3 = (const float*)d_in[24];
    const float* bl3 = (const float*)d_in[25];

    char* p = (char*)d_ws;
    auto carve = [&](size_t nbytes) {
        char* q = p;
        p += (nbytes + 255) & ~(size_t)255;
        return (void*)q;
    };
    float* x0    = (float*)carve((size_t)BB * NN * 3 * 4);
    float* sq    = (float*)carve((size_t)BB * NN * 4);
    float* negd  = (float*)carve((size_t)BB * NN * NN * 4);   // reused: hmin/hmax, then xc hi/lo
    int*   idx   = (int*)carve((size_t)BB * NN * KNN * 4);
    float* Wt    = (float*)carve((size_t)960 * 1024 * 4);     // fp32 Wt; W5 hi/lo overlays later
    float* uw    = (float*)carve((size_t)BB * NN * 1024 * 4); // u|w rows; also h5
    float* xc    = (float*)carve((size_t)BB * NN * 960 * 4);
    float* s1    = (float*)carve(2048 * 4);
    float* s2    = s1 + 1024;
    float* scale = (float*)carve(1024 * 4);
    float* shiftv= (float*)carve(1024 * 4);
    float* pmax  = (float*)carve((size_t)16 * BB * 1024 * 4);
    float* psum  = (float*)carve((size_t)16 * BB * 1024 * 4);
    float* z     = (float*)carve((size_t)BB * 2048 * 4);
    float* z1    = (float*)carve((size_t)BB * 512 * 4);
    float* z2    = (float*)carve((size_t)BB * 256 * 4);
    float* hmin  = negd;
    float* hmax  = negd + (size_t)BB * NN * 512;
    // block-5 overlays (regions dead by then):
    u16*   xcbh  = (u16*)negd;                                 // 8192*960 bf16 hi
    u16*   xcbl  = xcbh + (size_t)BB * NN * 960;               // lo  (together 31.5MB <= 33.5MB)
    u16*   W5bh  = (u16*)Wt;                                   // 1024*960 bf16 hi
    u16*   W5bl  = W5bh + (size_t)1024 * 960;                  // lo  (together 3.75MB <= 3.93MB)

    k_transpose<<<dim3((BB * NN + 255) / 256), dim3(256), 0, stream>>>(x, x0);

    const float* Ws[4] = {W1, W2, W3, W4};
    const float* gs[4] = {g1, g2, g3, g4};
    const float* bs[4] = {b1, b2, b3, b4};
    int Cs[4] = {3, 64, 128, 256};
    int Os[4] = {64, 128, 256, 512};
    const float* xins[4] = {x0, xc + 0, xc + 64, xc + 192};
    int SAs[4] = {3, 960, 960, 960};
    int coloff[4] = {0, 64, 192, 448};

    for (int blk = 0; blk < 4; ++blk) {
        int C = Cs[blk], O = Os[blk];
        const float* xin = xins[blk];
        int SA = SAs[blk];
        k_rowsq<<<dim3(32), dim3(256), 0, stream>>>(xin, C, SA, sq);
        k_gemm128<1><<<dim3(NN / 128, NN / 128, BB), dim3(256), 0, stream>>>(
            xin, SA, xin, negd, C, NN, sq);
        k_topk<<<dim3(BB * NN / 4), dim3(256), 0, stream>>>(negd, idx);
        k_prep_wt<<<dim3((C * O + 255) / 256), dim3(256), 0, stream>>>(Ws[blk], C, O, Wt);
        k_gemm128<0><<<dim3(2 * O / 128, BB * NN / 128, 1), dim3(256), 0, stream>>>(
            xin, SA, Wt, uw, C, 2 * O, (const float*)nullptr);
        hipMemsetAsync(s1, 0, 2048 * 4, stream);
        k_gather_stats<<<dim3(BB * NN / 16), dim3(256), 0, stream>>>(uw, idx, O, hmin, hmax, s1, s2);
        k_bn_fin<<<dim3((O + 255) / 256), dim3(256), 0, stream>>>(
            s1, s2, gs[blk], bs[blk], 1.0f / ((float)BB * NN * KNN), O, scale, shiftv);
        k_apply<<<dim3(BB * NN), dim3(128), 0, stream>>>(hmin, hmax, scale, shiftv, O,
                                                         xc + coloff[blk], 960);
    }

    // ---- block 5: h5 = xc @ W5^T via split-bf16 MFMA (~fp32 accuracy) ----
    k_cvt_split<<<dim3((1024 * 240 + 255) / 256), dim3(256), 0, stream>>>(
        W5, 960, 960, 1024, W5bh, W5bl);
    k_cvt_split<<<dim3((BB * NN * 240 + 255) / 256), dim3(256), 0, stream>>>(
        xc, 960, 960, BB * NN, xcbh, xcbl);
    k_mfma_bt_split<<<dim3(1024 / 128, BB * NN / 128), dim3(256), 0, stream>>>(
        xcbh, xcbl, 960, W5bh, W5bl, 960, uw, 1024, 960);
    hipMemsetAsync(s1, 0, 2048 * 4, stream);
    k_colstats<<<dim3(4, BB * NN / 64), dim3(256), 0, stream>>>(uw, 1024, s1, s2);
    k_bn_fin<<<dim3(4), dim3(256), 0, stream>>>(s1, s2, g5, b5, 1.0f / ((float)BB * NN), 1024,
                                                scale, shiftv);
    k_apply5<<<dim3(4, 16, BB), dim3(256), 0, stream>>>(uw, scale, shiftv, pmax, psum);
    k_zfin<<<dim3(4, BB), dim3(256), 0, stream>>>(pmax, psum, z);

    // ---- FC head ----
    k_fc<<<dim3(512), dim3(64), 0, stream>>>(z, 2048, Wl1, (const float*)nullptr, z1, 512);
    k_fcbn<<<dim3(2), dim3(256), 0, stream>>>(z1, g6, b6, 512);
    k_fc<<<dim3(256), dim3(64), 0, stream>>>(z1, 512, Wl2, bl2, z2, 256);
    k_fcbn<<<dim3(1), dim3(256), 0, stream>>>(z2, g7, b7, 256);
    k_fc<<<dim3(40), dim3(64), 0, stream>>>(z2, 256, Wl3, bl3, (float*)d_out, 40);
}